// Round 1
// baseline (127.492 us; speedup 1.0000x reference)
//
#include <hip/hip_runtime.h>
#include <hip/hip_bf16.h>

// Sliding-window attention, B=1 H=16 S=8192 D=64, window = +/- w (w=256 at bench).
// fp32 in/out; bf16 MFMA compute with fp32 accumulation + online softmax.

#define NH  16
#define SEQ 8192
#define HD  64
#define QT  128      // q rows per workgroup
#define NW  4        // waves per workgroup
#define NEGV -1e30f

typedef __bf16 bf16x8 __attribute__((ext_vector_type(8)));
typedef __bf16 bf16x4 __attribute__((ext_vector_type(4)));
typedef float  f32x4  __attribute__((ext_vector_type(4)));

__global__ __launch_bounds__(256) void swa_fwd(
    const float* __restrict__ Q, const float* __restrict__ K,
    const float* __restrict__ V, float* __restrict__ O,
    const int* __restrict__ wsz)
{
    const int w    = wsz[0];
    const int h    = blockIdx.y;
    const int q0   = blockIdx.x * QT;
    const int tid  = threadIdx.x;
    const int lane = tid & 63;
    const int wv   = tid >> 6;
    const int l15  = lane & 15;
    const int g    = lane >> 4;

    const size_t hoff = (size_t)h * SEQ * HD;
    const float* Qh = Q + hoff;
    const float* Kh = K + hoff;
    const float* Vh = V + hoff;
    float*       Oh = O + hoff;

    // K tile: [32 keys][64 d] bf16, XOR-swizzled (G4: stride-128B b128 reads).
    // V tile: transposed [64 d][40 keys] (pad->2-way max on b128 frag reads).
    // P tile: per-wave [16 q][36 keys] (stride 72B: write+read conflict-free).
    __shared__ __align__(16) __bf16 Ks[32 * 64];
    __shared__ __align__(16) __bf16 Vt[64 * 40];
    __shared__ __align__(16) __bf16 Pl[NW][16 * 36];

    // ---- Q fragments (scale 1/8 folded in before bf16 cast) ----
    // A-frag layout: row = lane&15, k = (lane>>4)*8 + j
    bf16x8 qf[2][2];
#pragma unroll
    for (int rb = 0; rb < 2; ++rb)
#pragma unroll
        for (int ks = 0; ks < 2; ++ks) {
            const float* src = Qh + (size_t)(q0 + wv*32 + rb*16 + l15) * HD + ks*32 + g*8;
            float4 a = *(const float4*)src;
            float4 b = *(const float4*)(src + 4);
            bf16x8 t;
            t[0] = (__bf16)(a.x * 0.125f); t[1] = (__bf16)(a.y * 0.125f);
            t[2] = (__bf16)(a.z * 0.125f); t[3] = (__bf16)(a.w * 0.125f);
            t[4] = (__bf16)(b.x * 0.125f); t[5] = (__bf16)(b.y * 0.125f);
            t[6] = (__bf16)(b.z * 0.125f); t[7] = (__bf16)(b.w * 0.125f);
            qf[rb][ks] = t;
        }

    f32x4 acc[2][4];    // [rb][dblk], C-layout: row=(g*4+r), col=dblk*16+l15
    float mr[2][4], lr[2][4];
#pragma unroll
    for (int rb = 0; rb < 2; ++rb)
#pragma unroll
        for (int r = 0; r < 4; ++r) {
            mr[rb][r] = NEGV; lr[rb][r] = 0.f;
#pragma unroll
            for (int db = 0; db < 4; ++db) acc[rb][db][r] = 0.f;
        }

    int kv_lo = q0 - w; if (kv_lo < 0) kv_lo = 0; kv_lo &= ~31;
    int kv_hi = q0 + QT + w; if (kv_hi > SEQ) kv_hi = SEQ;
    kv_hi = (kv_hi + 31) & ~31;   // SEQ%32==0 so this never exceeds SEQ

    const int rw0 = q0 + wv * 32;

    for (int kb = kv_lo; kb < kv_hi; kb += 32) {
        // ---- stage K (coalesced f32 loads, bf16 swizzled LDS write) ----
        {
            const int key = tid >> 3, d8 = (tid & 7) * 8;
            const float* src = Kh + (size_t)(kb + key) * HD + d8;
            float4 a = *(const float4*)src;
            float4 b = *(const float4*)(src + 4);
            bf16x8 t;
            t[0]=(__bf16)a.x; t[1]=(__bf16)a.y; t[2]=(__bf16)a.z; t[3]=(__bf16)a.w;
            t[4]=(__bf16)b.x; t[5]=(__bf16)b.y; t[6]=(__bf16)b.z; t[7]=(__bf16)b.w;
            *(bf16x8*)&Ks[key*64 + (d8 ^ ((key & 7) << 3))] = t;
        }
        // ---- stage V transposed: thread owns one d (=lane), 8 keys ----
        {
            const int d = tid & 63, kq = tid >> 6;
            bf16x8 t;
#pragma unroll
            for (int i = 0; i < 8; ++i)
                t[i] = (__bf16)Vh[(size_t)(kb + kq*8 + i) * HD + d];
            *(bf16x8*)&Vt[d*40 + kq*8] = t;
        }
        __syncthreads();

        if (kb <= rw0 + 31 + w && kb + 31 >= rw0 - w) {
            // K B-frags: col=key=c*16+l15, k=d=ks*32+g*8+j
            bf16x8 kf[2][2];
#pragma unroll
            for (int c = 0; c < 2; ++c)
#pragma unroll
                for (int ks = 0; ks < 2; ++ks) {
                    const int row = c*16 + l15;
                    kf[c][ks] = *(const bf16x8*)&Ks[row*64 + ((ks*32 + g*8) ^ ((row & 7) << 3))];
                }
            // V B-frags: col=d=db*16+l15, k=key=g*8+j
            bf16x8 vf[4];
#pragma unroll
            for (int db = 0; db < 4; ++db)
                vf[db] = *(const bf16x8*)&Vt[(db*16 + l15)*40 + g*8];

#pragma unroll
            for (int rb = 0; rb < 2; ++rb) {
                const int r0b = rw0 + rb*16;
                if (kb > r0b + 15 + w || kb + 31 < r0b - w) continue;

                f32x4 s0 = {0.f,0.f,0.f,0.f}, s1 = {0.f,0.f,0.f,0.f};
                s0 = __builtin_amdgcn_mfma_f32_16x16x32_bf16(qf[rb][0], kf[0][0], s0, 0,0,0);
                s0 = __builtin_amdgcn_mfma_f32_16x16x32_bf16(qf[rb][1], kf[0][1], s0, 0,0,0);
                s1 = __builtin_amdgcn_mfma_f32_16x16x32_bf16(qf[rb][0], kf[1][0], s1, 0,0,0);
                s1 = __builtin_amdgcn_mfma_f32_16x16x32_bf16(qf[rb][1], kf[1][1], s1, 0,0,0);

                const bool full = (kb + 31 - r0b <= w) && (kb - (r0b + 15) >= -w);
                if (!full) {
#pragma unroll
                    for (int r = 0; r < 4; ++r) {
                        const int i  = r0b + g*4 + r;
                        const int d0 = kb + l15 - i;
                        if (d0 < -w || d0 > w)           s0[r] = NEGV;
                        const int d1 = d0 + 16;
                        if (d1 < -w || d1 > w)           s1[r] = NEGV;
                    }
                }

                // online softmax (rows live in 16-lane groups; xor 1,2,4,8 reduces cols)
                float f[4], ps0[4], ps1[4];
#pragma unroll
                for (int r = 0; r < 4; ++r) {
                    float rm = fmaxf(s0[r], s1[r]);
                    rm = fmaxf(rm, __shfl_xor(rm, 1));
                    rm = fmaxf(rm, __shfl_xor(rm, 2));
                    rm = fmaxf(rm, __shfl_xor(rm, 4));
                    rm = fmaxf(rm, __shfl_xor(rm, 8));
                    const float mn = fmaxf(mr[rb][r], rm);
                    f[r] = __expf(mr[rb][r] - mn);
                    mr[rb][r] = mn;
                    const float p0 = __expf(s0[r] - mn);
                    const float p1 = __expf(s1[r] - mn);
                    ps0[r] = p0; ps1[r] = p1;
                    float sum = p0 + p1;
                    sum += __shfl_xor(sum, 1);
                    sum += __shfl_xor(sum, 2);
                    sum += __shfl_xor(sum, 4);
                    sum += __shfl_xor(sum, 8);
                    lr[rb][r] = lr[rb][r] * f[r] + sum;
                }
#pragma unroll
                for (int db = 0; db < 4; ++db)
#pragma unroll
                    for (int r = 0; r < 4; ++r)
                        acc[rb][db][r] *= f[r];

                // P -> LDS (bf16), reread in A-frag layout (same-wave, ds in-order)
                __bf16* Pw = &Pl[wv][0];
#pragma unroll
                for (int r = 0; r < 4; ++r) {
                    const int row = g*4 + r;
                    Pw[row*36 + l15]      = (__bf16)ps0[r];
                    Pw[row*36 + 16 + l15] = (__bf16)ps1[r];
                }
                bf16x4 lo = *(const bf16x4*)&Pw[l15*36 + g*8];
                bf16x4 hi = *(const bf16x4*)&Pw[l15*36 + g*8 + 4];
                bf16x8 pf = __builtin_shufflevector(lo, hi, 0,1,2,3,4,5,6,7);
#pragma unroll
                for (int db = 0; db < 4; ++db)
                    acc[rb][db] = __builtin_amdgcn_mfma_f32_16x16x32_bf16(pf, vf[db], acc[rb][db], 0,0,0);
            }
        }
        __syncthreads();
    }

    // ---- epilogue: normalize + store (coalesced 4x64B per instr) ----
#pragma unroll
    for (int rb = 0; rb < 2; ++rb) {
        float inv[4];
#pragma unroll
        for (int r = 0; r < 4; ++r) inv[r] = 1.0f / lr[rb][r];
#pragma unroll
        for (int db = 0; db < 4; ++db)
#pragma unroll
            for (int r = 0; r < 4; ++r) {
                const int row = q0 + wv*32 + rb*16 + g*4 + r;
                Oh[(size_t)row * HD + db*16 + l15] = acc[rb][db][r] * inv[r];
            }
    }
}

extern "C" void kernel_launch(void* const* d_in, const int* in_sizes, int n_in,
                              void* d_out, int out_size, void* d_ws, size_t ws_size,
                              hipStream_t stream) {
    const float* Q   = (const float*)d_in[0];
    const float* K   = (const float*)d_in[1];
    const float* V   = (const float*)d_in[2];
    const int*   wsz = (const int*)d_in[4];   // window_size (batch_size=d_in[3] unused, B=1)
    float* O = (float*)d_out;
    dim3 grid(SEQ / QT, NH, 1);
    swa_fwd<<<grid, dim3(64 * NW), 0, stream>>>(Q, K, V, O, wsz);
}

// Round 2
// 79.430 us; speedup vs baseline: 1.6051x; 1.6051x over previous
//
#include <hip/hip_runtime.h>
#include <hip/hip_bf16.h>

// Sliding-window attention, B=1 H=16 S=8192 D=64, window +/- w (w=256 at bench).
// fp32 in/out; bf16 MFMA, fp32 accum, online softmax in exp2 domain.
// R2: swapped QK^T (S^T, row-per-lane softmax), KVB=64, reg-prefetch staging,
//     defer-max rescale skip, packed P->LDS.

#define NH  16
#define SEQ 8192
#define HD  64
#define QT  128      // q rows per workgroup
#define NW  4        // waves per workgroup
#define KVB 64       // keys per iteration
#define NEGV -1e30f
#define RESCALE_T 11.5f   // ~8 nats in log2 domain

typedef __bf16 bf16x8 __attribute__((ext_vector_type(8)));
typedef __bf16 bf16x4 __attribute__((ext_vector_type(4)));
typedef float  f32x4  __attribute__((ext_vector_type(4)));

__global__ __launch_bounds__(256) void swa_fwd(
    const float* __restrict__ Q, const float* __restrict__ K,
    const float* __restrict__ V, float* __restrict__ O,
    const int* __restrict__ wsz)
{
    const int w    = wsz[0];
    const int w2   = 2 * w;
    const int h    = blockIdx.y;
    const int q0   = blockIdx.x * QT;
    const int tid  = threadIdx.x;
    const int lane = tid & 63;
    const int wv   = tid >> 6;
    const int l15  = lane & 15;
    const int g    = lane >> 4;

    const size_t hoff = (size_t)h * SEQ * HD;
    const float* Qh = Q + hoff;
    const float* Kh = K + hoff;
    const float* Vh = V + hoff;
    float*       Oh = O + hoff;

    // K: [64 keys][64 d] bf16, XOR-swizzled (row-stride 128B would be 32-way).
    // Vt: transposed [64 d][72 keys] (stride 144B -> min-cycle b128 reads).
    // Pl: per-wave [16 q][68 keys] (stride 136B -> conflict-free b64 w/b128 r).
    __shared__ __align__(16) __bf16 Ks[KVB * 64];
    __shared__ __align__(16) __bf16 Vt[64 * 72];
    __shared__ __align__(16) __bf16 Pl[NW][16 * 68];

    // ---- Q fragments, used as MFMA B-operand (col=q=l15, k=d=g*8+j) ----
    // scale = D^-0.5 * log2(e): scores land in log2 domain.
    const float qscale = 0.125f * 1.44269504f;
    bf16x8 qf[2][2];
#pragma unroll
    for (int rb = 0; rb < 2; ++rb)
#pragma unroll
        for (int ks = 0; ks < 2; ++ks) {
            const float* src = Qh + (size_t)(q0 + wv*32 + rb*16 + l15) * HD + ks*32 + g*8;
            float4 a = *(const float4*)src;
            float4 b = *(const float4*)(src + 4);
            bf16x8 t;
            t[0] = (__bf16)(a.x * qscale); t[1] = (__bf16)(a.y * qscale);
            t[2] = (__bf16)(a.z * qscale); t[3] = (__bf16)(a.w * qscale);
            t[4] = (__bf16)(b.x * qscale); t[5] = (__bf16)(b.y * qscale);
            t[6] = (__bf16)(b.z * qscale); t[7] = (__bf16)(b.w * qscale);
            qf[rb][ks] = t;
        }

    f32x4 acc[2][4];              // [rb][dblk]; row q = g*4+r, col d = db*16+l15
    float mr[2] = {NEGV, NEGV};   // softmax state lives at q = l15 (all g copies)
    float lr[2] = {0.f, 0.f};
#pragma unroll
    for (int rb = 0; rb < 2; ++rb)
#pragma unroll
        for (int db = 0; db < 4; ++db)
            acc[rb][db] = f32x4{0.f, 0.f, 0.f, 0.f};

    int kv_lo = q0 - w; if (kv_lo < 0) kv_lo = 0; kv_lo &= ~(KVB - 1);
    int kv_hi = q0 + QT + w; if (kv_hi > SEQ) kv_hi = SEQ;
    kv_hi = (kv_hi + KVB - 1) & ~(KVB - 1);

    const int rw0 = q0 + wv * 32;

    // ---- prefetch registers (T14: issue loads early, LDS-write late) ----
    const int kkey = tid >> 2, kd4 = (tid & 3) * 4;   // K: 1/4 row each
    const int vd   = tid & 63, vk0 = (tid >> 6) * 16; // V: one d, 16 keys
    float4 kp[4];
    float  vp[16];

    {   // prologue preload
        const float* ks = Kh + (size_t)(kv_lo + kkey) * HD + kd4;
        kp[0] = *(const float4*)ks;        kp[1] = *(const float4*)(ks + 16);
        kp[2] = *(const float4*)(ks + 32); kp[3] = *(const float4*)(ks + 48);
        const float* vs = Vh + (size_t)(kv_lo + vk0) * HD + vd;
#pragma unroll
        for (int j = 0; j < 16; ++j) vp[j] = vs[j * HD];
    }

    for (int kb = kv_lo; kb < kv_hi; kb += KVB) {
        // ---- LDS store from prefetch regs ----
        {
            const int swk = (kkey & 7) << 3;
#pragma unroll
            for (int i = 0; i < 4; ++i) {
                bf16x4 t;
                t[0] = (__bf16)kp[i].x; t[1] = (__bf16)kp[i].y;
                t[2] = (__bf16)kp[i].z; t[3] = (__bf16)kp[i].w;
                *(bf16x4*)&Ks[kkey*64 + ((kd4 + 16*i) ^ swk)] = t;
            }
            bf16x8 t0, t1;
#pragma unroll
            for (int j = 0; j < 8; ++j) { t0[j] = (__bf16)vp[j]; t1[j] = (__bf16)vp[8+j]; }
            *(bf16x8*)&Vt[vd*72 + vk0]     = t0;
            *(bf16x8*)&Vt[vd*72 + vk0 + 8] = t1;
        }
        // ---- issue next block's global loads (overlap with compute) ----
        if (kb + KVB < kv_hi) {
            const float* ks = Kh + (size_t)(kb + KVB + kkey) * HD + kd4;
            kp[0] = *(const float4*)ks;        kp[1] = *(const float4*)(ks + 16);
            kp[2] = *(const float4*)(ks + 32); kp[3] = *(const float4*)(ks + 48);
            const float* vs = Vh + (size_t)(kb + KVB + vk0) * HD + vd;
#pragma unroll
            for (int j = 0; j < 16; ++j) vp[j] = vs[j * HD];
        }
        __syncthreads();

        if (kb <= rw0 + 31 + w && kb + KVB - 1 >= rw0 - w) {
            const int sw = (l15 & 7) << 3;
#pragma unroll
            for (int rb = 0; rb < 2; ++rb) {
                const int r0b = rw0 + rb * 16;
                if (kb > r0b + 15 + w || kb + KVB - 1 < r0b - w) continue;

                // ---- S^T = K x Q : D[key][q], q = l15, key = t*16 + g*4 + r
                f32x4 st[4];
#pragma unroll
                for (int t = 0; t < 4; ++t) {
                    bf16x8 kf0 = *(const bf16x8*)&Ks[(t*16 + l15)*64 + ((      g*8) ^ sw)];
                    bf16x8 kf1 = *(const bf16x8*)&Ks[(t*16 + l15)*64 + ((32 + g*8) ^ sw)];
                    f32x4 z{0.f, 0.f, 0.f, 0.f};
                    z = __builtin_amdgcn_mfma_f32_16x16x32_bf16(kf0, qf[rb][0], z, 0,0,0);
                    st[t] = __builtin_amdgcn_mfma_f32_16x16x32_bf16(kf1, qf[rb][1], z, 0,0,0);
                }

                const bool full = (kb + KVB-1 - r0b <= w) && (kb - (r0b + 15) >= -w);
                if (!full) {
                    const int relb = kb + 4*g - r0b - l15 + w;   // rel+w
#pragma unroll
                    for (int t = 0; t < 4; ++t)
#pragma unroll
                        for (int r = 0; r < 4; ++r)
                            if ((unsigned)(relb + 16*t + r) > (unsigned)w2)
                                st[t][r] = NEGV;
                }

                // ---- row max: in-lane tree + 2 shfls (row = q = l15) ----
                float m01 = fmaxf(fmaxf(st[0][0], st[0][1]), fmaxf(st[0][2], st[0][3]));
                float m23 = fmaxf(fmaxf(st[1][0], st[1][1]), fmaxf(st[1][2], st[1][3]));
                float m45 = fmaxf(fmaxf(st[2][0], st[2][1]), fmaxf(st[2][2], st[2][3]));
                float m67 = fmaxf(fmaxf(st[3][0], st[3][1]), fmaxf(st[3][2], st[3][3]));
                float rm = fmaxf(fmaxf(m01, m23), fmaxf(m45, m67));
                rm = fmaxf(rm, __shfl_xor(rm, 16));
                rm = fmaxf(rm, __shfl_xor(rm, 32));

                float m;
                if (__all(rm <= mr[rb] + RESCALE_T)) {      // T13 defer-max
                    m = mr[rb];
                } else {
                    m = fmaxf(mr[rb], rm);
                    const float f = __builtin_amdgcn_exp2f(mr[rb] - m);
                    mr[rb] = m;
                    lr[rb] *= f;
                    float fr[4];
#pragma unroll
                    for (int r = 0; r < 4; ++r) fr[r] = __shfl(f, g*4 + r);
#pragma unroll
                    for (int db = 0; db < 4; ++db)
#pragma unroll
                        for (int r = 0; r < 4; ++r) acc[rb][db][r] *= fr[r];
                }

                // ---- p = exp2(s - m), row-sum: in-lane tree + 2 shfls ----
                float p[4][4];
#pragma unroll
                for (int t = 0; t < 4; ++t)
#pragma unroll
                    for (int r = 0; r < 4; ++r)
                        p[t][r] = __builtin_amdgcn_exp2f(st[t][r] - m);
                float s01 = (p[0][0] + p[0][1]) + (p[0][2] + p[0][3]);
                float s23 = (p[1][0] + p[1][1]) + (p[1][2] + p[1][3]);
                float s45 = (p[2][0] + p[2][1]) + (p[2][2] + p[2][3]);
                float s67 = (p[3][0] + p[3][1]) + (p[3][2] + p[3][3]);
                float sum = (s01 + s23) + (s45 + s67);
                sum += __shfl_xor(sum, 16);
                sum += __shfl_xor(sum, 32);
                lr[rb] += sum;

                // ---- P -> LDS (packed b64 per tile), reread as A-frag ----
                __bf16* Pw = &Pl[wv][0];
#pragma unroll
                for (int t = 0; t < 4; ++t) {
                    bf16x4 pk;
                    pk[0] = (__bf16)p[t][0]; pk[1] = (__bf16)p[t][1];
                    pk[2] = (__bf16)p[t][2]; pk[3] = (__bf16)p[t][3];
                    *(bf16x4*)&Pw[l15*68 + t*16 + g*4] = pk;
                }
#pragma unroll
                for (int kh = 0; kh < 2; ++kh) {
                    bf16x8 pf = *(const bf16x8*)&Pw[l15*68 + kh*32 + g*8];
#pragma unroll
                    for (int db = 0; db < 4; ++db) {
                        bf16x8 vfr = *(const bf16x8*)&Vt[(db*16 + l15)*72 + kh*32 + g*8];
                        acc[rb][db] = __builtin_amdgcn_mfma_f32_16x16x32_bf16(pf, vfr, acc[rb][db], 0,0,0);
                    }
                }
            }
        }
        __syncthreads();
    }

    // ---- epilogue: lr lives at q=l15; acc rows at q=g*4+r -> shfl ----
#pragma unroll
    for (int rb = 0; rb < 2; ++rb) {
        const float il = 1.0f / lr[rb];
        float inv[4];
#pragma unroll
        for (int r = 0; r < 4; ++r) inv[r] = __shfl(il, g*4 + r);
#pragma unroll
        for (int db = 0; db < 4; ++db)
#pragma unroll
            for (int r = 0; r < 4; ++r) {
                const int row = q0 + wv*32 + rb*16 + g*4 + r;
                Oh[(size_t)row * HD + db*16 + l15] = acc[rb][db][r] * inv[r];
            }
    }
}

extern "C" void kernel_launch(void* const* d_in, const int* in_sizes, int n_in,
                              void* d_out, int out_size, void* d_ws, size_t ws_size,
                              hipStream_t stream) {
    const float* Q   = (const float*)d_in[0];
    const float* K   = (const float*)d_in[1];
    const float* V   = (const float*)d_in[2];
    const int*   wsz = (const int*)d_in[4];   // window_size (d_in[3]=batch_size unused, B=1)
    float* O = (float*)d_out;
    dim3 grid(SEQ / QT, NH, 1);
    swa_fwd<<<grid, dim3(64 * NW), 0, stream>>>(Q, K, V, O, wsz);
}

// Round 3
// 69.370 us; speedup vs baseline: 1.8379x; 1.1450x over previous
//
#include <hip/hip_runtime.h>
#include <hip/hip_bf16.h>

// Sliding-window attention, B=1 H=16 S=8192 D=64, window +/- w (w=256 at bench).
// fp32 in/out; bf16 MFMA, fp32 accum, online softmax in exp2 domain.
// R3: K staged with permuted rows so S^T regs repack LOCALLY into the PV
//     A-fragment (P LDS roundtrip deleted); setprio around MFMA clusters.

#define NH  16
#define SEQ 8192
#define HD  64
#define QT  128      // q rows per workgroup
#define NW  4        // waves per workgroup
#define KVB 64       // keys per iteration
#define NEGV -1e30f
#define RESCALE_T 11.5f   // ~8 nats in log2 domain

typedef __bf16 bf16x8 __attribute__((ext_vector_type(8)));
typedef __bf16 bf16x4 __attribute__((ext_vector_type(4)));
typedef float  f32x4  __attribute__((ext_vector_type(4)));

__global__ __launch_bounds__(256) void swa_fwd(
    const float* __restrict__ Q, const float* __restrict__ K,
    const float* __restrict__ V, float* __restrict__ O,
    const int* __restrict__ wsz)
{
    const int w    = wsz[0];
    const int w2   = 2 * w;
    const int h    = blockIdx.y;
    const int q0   = blockIdx.x * QT;
    const int tid  = threadIdx.x;
    const int lane = tid & 63;
    const int wv   = tid >> 6;
    const int l15  = lane & 15;
    const int g    = lane >> 4;

    const size_t hoff = (size_t)h * SEQ * HD;
    const float* Qh = Q + hoff;
    const float* Kh = K + hoff;
    const float* Vh = V + hoff;
    float*       Oh = O + hoff;

    // Ks: [64 rows][64 d] bf16, XOR-swizzled; physical row rho holds ACTUAL key
    //     a(rho)= (t&1)*32 + g*8 + (t>>1)*4 + r  (t=rho>>4, i=rho&15, g=i>>2, r=i&3)
    //     so S^T output regs repack locally into the PV A-fragment.
    // Vt: transposed [64 d][72 keys] (natural key order; stride 144B min-cycle).
    __shared__ __align__(16) __bf16 Ks[KVB * 64];
    __shared__ __align__(16) __bf16 Vt[64 * 72];

    // ---- Q fragments, MFMA B-operand (col=q=l15, k=d=g*8+j) ----
    // scale = D^-0.5 * log2(e): scores in log2 domain.
    const float qscale = 0.125f * 1.44269504f;
    bf16x8 qf[2][2];
#pragma unroll
    for (int rb = 0; rb < 2; ++rb)
#pragma unroll
        for (int ks = 0; ks < 2; ++ks) {
            const float* src = Qh + (size_t)(q0 + wv*32 + rb*16 + l15) * HD + ks*32 + g*8;
            float4 a = *(const float4*)src;
            float4 b = *(const float4*)(src + 4);
            bf16x8 t;
            t[0] = (__bf16)(a.x * qscale); t[1] = (__bf16)(a.y * qscale);
            t[2] = (__bf16)(a.z * qscale); t[3] = (__bf16)(a.w * qscale);
            t[4] = (__bf16)(b.x * qscale); t[5] = (__bf16)(b.y * qscale);
            t[6] = (__bf16)(b.z * qscale); t[7] = (__bf16)(b.w * qscale);
            qf[rb][ks] = t;
        }

    f32x4 acc[2][4];              // [rb][dblk]; row q = g*4+r, col d = db*16+l15
    float mr[2] = {NEGV, NEGV};   // softmax state at q = l15 (replicated over g)
    float lr[2] = {0.f, 0.f};
#pragma unroll
    for (int rb = 0; rb < 2; ++rb)
#pragma unroll
        for (int db = 0; db < 4; ++db)
            acc[rb][db] = f32x4{0.f, 0.f, 0.f, 0.f};

    int kv_lo = q0 - w; if (kv_lo < 0) kv_lo = 0; kv_lo &= ~(KVB - 1);
    int kv_hi = q0 + QT + w; if (kv_hi > SEQ) kv_hi = SEQ;
    kv_hi = (kv_hi + KVB - 1) & ~(KVB - 1);

    const int rw0 = q0 + wv * 32;

    // ---- staging indices ----
    const int kkey = tid >> 2, kd4 = (tid & 3) * 4;   // kkey = ACTUAL key offset
    // physical row for actual key kkey (inverse of a(rho)):
    const int prow = ((kkey >> 2) & 1) * 32 + ((kkey >> 5) & 1) * 16
                   + ((kkey >> 3) & 3) * 4  + (kkey & 3);
    const int swk  = (prow & 7) << 3;
    const int vd   = tid & 63, vk0 = (tid >> 6) * 16; // V: one d, 16 keys

    float4 kp[4];
    float  vp[16];
    {   // prologue preload (T14: loads early, LDS-write late)
        const float* ks = Kh + (size_t)(kv_lo + kkey) * HD + kd4;
        kp[0] = *(const float4*)ks;        kp[1] = *(const float4*)(ks + 16);
        kp[2] = *(const float4*)(ks + 32); kp[3] = *(const float4*)(ks + 48);
        const float* vs = Vh + (size_t)(kv_lo + vk0) * HD + vd;
#pragma unroll
        for (int j = 0; j < 16; ++j) vp[j] = vs[j * HD];
    }

    for (int kb = kv_lo; kb < kv_hi; kb += KVB) {
        // ---- LDS store from prefetch regs ----
        {
#pragma unroll
            for (int i = 0; i < 4; ++i) {
                bf16x4 t;
                t[0] = (__bf16)kp[i].x; t[1] = (__bf16)kp[i].y;
                t[2] = (__bf16)kp[i].z; t[3] = (__bf16)kp[i].w;
                *(bf16x4*)&Ks[prow*64 + ((kd4 + 16*i) ^ swk)] = t;
            }
            bf16x8 t0, t1;
#pragma unroll
            for (int j = 0; j < 8; ++j) { t0[j] = (__bf16)vp[j]; t1[j] = (__bf16)vp[8+j]; }
            *(bf16x8*)&Vt[vd*72 + vk0]     = t0;
            *(bf16x8*)&Vt[vd*72 + vk0 + 8] = t1;
        }
        // ---- issue next block's global loads (overlap with compute) ----
        if (kb + KVB < kv_hi) {
            const float* ks = Kh + (size_t)(kb + KVB + kkey) * HD + kd4;
            kp[0] = *(const float4*)ks;        kp[1] = *(const float4*)(ks + 16);
            kp[2] = *(const float4*)(ks + 32); kp[3] = *(const float4*)(ks + 48);
            const float* vs = Vh + (size_t)(kb + KVB + vk0) * HD + vd;
#pragma unroll
            for (int j = 0; j < 16; ++j) vp[j] = vs[j * HD];
        }
        __syncthreads();

        if (kb <= rw0 + 31 + w && kb + KVB - 1 >= rw0 - w) {
            const int sw = (l15 & 7) << 3;
#pragma unroll
            for (int rb = 0; rb < 2; ++rb) {
                const int r0b = rw0 + rb * 16;
                if (kb > r0b + 15 + w || kb + KVB - 1 < r0b - w) continue;

                // ---- S^T = K x Q : st[t][r] = S[key=a(t,g,r)][q=l15] ----
                f32x4 st[4];
                __builtin_amdgcn_s_setprio(1);
#pragma unroll
                for (int t = 0; t < 4; ++t) {
                    bf16x8 kf0 = *(const bf16x8*)&Ks[(t*16 + l15)*64 + ((     g*8) ^ sw)];
                    bf16x8 kf1 = *(const bf16x8*)&Ks[(t*16 + l15)*64 + ((32 + g*8) ^ sw)];
                    f32x4 z{0.f, 0.f, 0.f, 0.f};
                    z     = __builtin_amdgcn_mfma_f32_16x16x32_bf16(kf0, qf[rb][0], z, 0,0,0);
                    st[t] = __builtin_amdgcn_mfma_f32_16x16x32_bf16(kf1, qf[rb][1], st[t]=z, 0,0,0);
                }
                __builtin_amdgcn_s_setprio(0);

                const bool full = (kb + KVB-1 - r0b <= w) && (kb - (r0b + 15) >= -w);
                if (!full) {
                    // actual key of st[t][r] = kb + (t&1)*32 + g*8 + (t>>1)*4 + r
                    const int relb = kb + g*8 + w - r0b - l15;
#pragma unroll
                    for (int t = 0; t < 4; ++t)
#pragma unroll
                        for (int r = 0; r < 4; ++r)
                            if ((unsigned)(relb + (t&1)*32 + (t>>1)*4 + r) > (unsigned)w2)
                                st[t][r] = NEGV;
                }

                // ---- row max: in-lane tree + 2 shfls (row = q = l15) ----
                float m01 = fmaxf(fmaxf(st[0][0], st[0][1]), fmaxf(st[0][2], st[0][3]));
                float m23 = fmaxf(fmaxf(st[1][0], st[1][1]), fmaxf(st[1][2], st[1][3]));
                float m45 = fmaxf(fmaxf(st[2][0], st[2][1]), fmaxf(st[2][2], st[2][3]));
                float m67 = fmaxf(fmaxf(st[3][0], st[3][1]), fmaxf(st[3][2], st[3][3]));
                float rm = fmaxf(fmaxf(m01, m23), fmaxf(m45, m67));
                rm = fmaxf(rm, __shfl_xor(rm, 16));
                rm = fmaxf(rm, __shfl_xor(rm, 32));

                float m;
                if (__all(rm <= mr[rb] + RESCALE_T)) {      // T13 defer-max
                    m = mr[rb];
                } else {
                    m = fmaxf(mr[rb], rm);
                    const float f = __builtin_amdgcn_exp2f(mr[rb] - m);
                    mr[rb] = m;
                    lr[rb] *= f;
                    float fr[4];
#pragma unroll
                    for (int r = 0; r < 4; ++r) fr[r] = __shfl(f, g*4 + r);
#pragma unroll
                    for (int db = 0; db < 4; ++db)
#pragma unroll
                        for (int r = 0; r < 4; ++r) acc[rb][db][r] *= fr[r];
                }
                // all-masked-row guard: keeps exp2(NEGV-NEGV)=1 from happening
                const float mm = fmaxf(m, -1e28f);

                // ---- p = exp2(s - m); row-sum: in-lane tree + 2 shfls ----
                float p[4][4];
#pragma unroll
                for (int t = 0; t < 4; ++t)
#pragma unroll
                    for (int r = 0; r < 4; ++r)
                        p[t][r] = __builtin_amdgcn_exp2f(st[t][r] - mm);
                float s01 = (p[0][0] + p[0][1]) + (p[0][2] + p[0][3]);
                float s23 = (p[1][0] + p[1][1]) + (p[1][2] + p[1][3]);
                float s45 = (p[2][0] + p[2][1]) + (p[2][2] + p[2][3]);
                float s67 = (p[3][0] + p[3][1]) + (p[3][2] + p[3][3]);
                float sum = (s01 + s23) + (s45 + s67);
                sum += __shfl_xor(sum, 16);
                sum += __shfl_xor(sum, 32);
                lr[rb] += sum;

                // ---- LOCAL repack into PV A-frag (key-permuted K makes this
                //      lane-local): pf[kh] = {p[kh][0..3], p[kh+2][0..3]} ----
#pragma unroll
                for (int kh = 0; kh < 2; ++kh) {
                    bf16x8 pf;
                    pf[0] = (__bf16)p[kh][0];   pf[1] = (__bf16)p[kh][1];
                    pf[2] = (__bf16)p[kh][2];   pf[3] = (__bf16)p[kh][3];
                    pf[4] = (__bf16)p[kh+2][0]; pf[5] = (__bf16)p[kh+2][1];
                    pf[6] = (__bf16)p[kh+2][2]; pf[7] = (__bf16)p[kh+2][3];
                    __builtin_amdgcn_s_setprio(1);
#pragma unroll
                    for (int db = 0; db < 4; ++db) {
                        bf16x8 vfr = *(const bf16x8*)&Vt[(db*16 + l15)*72 + kh*32 + g*8];
                        acc[rb][db] = __builtin_amdgcn_mfma_f32_16x16x32_bf16(pf, vfr, acc[rb][db], 0,0,0);
                    }
                    __builtin_amdgcn_s_setprio(0);
                }
            }
        }
        __syncthreads();
    }

    // ---- epilogue: lr at q=l15; acc rows at q=g*4+r -> shfl ----
#pragma unroll
    for (int rb = 0; rb < 2; ++rb) {
        const float il = 1.0f / lr[rb];
        float inv[4];
#pragma unroll
        for (int r = 0; r < 4; ++r) inv[r] = __shfl(il, g*4 + r);
#pragma unroll
        for (int db = 0; db < 4; ++db)
#pragma unroll
            for (int r = 0; r < 4; ++r) {
                const int row = q0 + wv*32 + rb*16 + g*4 + r;
                Oh[(size_t)row * HD + db*16 + l15] = acc[rb][db][r] * inv[r];
            }
    }
}

extern "C" void kernel_launch(void* const* d_in, const int* in_sizes, int n_in,
                              void* d_out, int out_size, void* d_ws, size_t ws_size,
                              hipStream_t stream) {
    const float* Q   = (const float*)d_in[0];
    const float* K   = (const float*)d_in[1];
    const float* V   = (const float*)d_in[2];
    const int*   wsz = (const int*)d_in[4];   // window_size (d_in[3]=batch_size unused)
    float* O = (float*)d_out;
    dim3 grid(SEQ / QT, NH, 1);
    swa_fwd<<<grid, dim3(64 * NW), 0, stream>>>(Q, K, V, O, wsz);
}